// Round 8
// baseline (131.927 us; speedup 1.0000x reference)
//
#include <hip/hip_runtime.h>

#define L 2048
#define H 8
#define S 128
#define B 8
#define HS 1024

// ============ KA: fused {E,Z prefix-scan} + partial_q ============
// grid (B, 32). Every block recomputes its own 64x8 exp(W) slice in LDS.
// Blocks (b==0, jc<8) additionally do the full prefix scan for h=jc -> E,Z.
// Block (0,0) also zeroes the one-shot gate counters (used later by kD/kF).
__global__ __launch_bounds__(256) void kA_prep_qpart(const float* __restrict__ W,
                                                     const float* __restrict__ x,
                                                     float* __restrict__ E,
                                                     float* __restrict__ Z,
                                                     float* __restrict__ partial_q,
                                                     unsigned* __restrict__ counters) {
  const int b = blockIdx.x, jc = blockIdx.y;
  const int t = threadIdx.x;
  if (b == 0 && jc == 0 && t < 144) counters[t] = 0u;   // 128 kD gates + 1 kF gate

  __shared__ float ew[64][H];       // ew[i][h] = E[h, L-1-(base+i)]
  __shared__ float part[8][H][S];   // [r][h][s]
  __shared__ float tot[256];        // scan scratch

  const int base = jc * 64;
  const int dhi = L - 1 - base;
#pragma unroll
  for (int k = 0; k < 2; ++k) {
    const int idx = t + k * 256;    // [0,512): i = idx>>3, h = idx&7
    const int i = idx >> 3, h = idx & 7;
    ew[i][h] = expf(W[(size_t)(dhi - i) * H + h]);
  }

  // --- full prefix scan for one h (8 blocks only) ---
  if (b == 0 && jc < H) {
    const int h = jc;
    const int d0 = t * 8;
    float e[8];
    float run = 0.f;
#pragma unroll
    for (int k = 0; k < 8; ++k) {
      float v = expf(W[(size_t)(d0 + k) * H + h]);
      e[k] = v; run += v;
    }
    tot[t] = run;
    __syncthreads();
    for (int off = 1; off < 256; off <<= 1) {
      float v = (t >= off) ? tot[t - off] : 0.f;
      __syncthreads();
      tot[t] += v;
      __syncthreads();
    }
    float c = (t == 0) ? 0.f : tot[t - 1];
#pragma unroll
    for (int k = 0; k < 8; ++k) {
      c += e[k];
      E[h * L + d0 + k] = e[k];
      Z[h * L + d0 + k] = c;
    }
  }
  __syncthreads();   // ew ready (and scan done)

  // --- partial_q main loop ---
  const int s4 = t & 31;
  const int r = t >> 5;
  const float4* __restrict__ x4 = (const float4*)(x + (size_t)b * L * S);
  float4 acc[H];
#pragma unroll
  for (int h = 0; h < H; ++h) acc[h] = make_float4(0.f, 0.f, 0.f, 0.f);
#pragma unroll
  for (int k = 0; k < 8; ++k) {
    const int ll = k * 8 + r;
    const int l = base + ll;
    const float4 xv = x4[(size_t)l * 32 + s4];
#pragma unroll
    for (int h = 0; h < H; ++h) {
      const float w = ew[ll][h];
      acc[h].x += w * xv.x; acc[h].y += w * xv.y;
      acc[h].z += w * xv.z; acc[h].w += w * xv.w;
    }
  }
#pragma unroll
  for (int h = 0; h < H; ++h) {
    part[r][h][s4 * 4 + 0] = acc[h].x;
    part[r][h][s4 * 4 + 1] = acc[h].y;
    part[r][h][s4 * 4 + 2] = acc[h].z;
    part[r][h][s4 * 4 + 3] = acc[h].w;
  }
  __syncthreads();
#pragma unroll
  for (int k = 0; k < 4; ++k) {
    const int idx = t + k * 256;           // h*S + s
    const int h = idx >> 7, s = idx & 127;
    float sm = 0.f;
#pragma unroll
    for (int rr = 0; rr < 8; ++rr) sm += part[rr][h][s];
    partial_q[((size_t)b * 32 + jc) * HS + idx] = sm;
  }
}

// ============ KB: all-batch GEMV over one A-chunk ============
// grid (4 ec, 16 dc). Phase 1: ql[b][dl] from partial_q (invZ folded, h uniform/block).
// Phase 2: partial_v[b,dc,e] = sum_d ql[b][d] * A[dbase+d, e]. A traffic = 4 MB total.
__global__ __launch_bounds__(256) void kB_v(const float* __restrict__ partial_q,
                                            const float* __restrict__ Z,
                                            const float* __restrict__ A,
                                            float* __restrict__ partial_v) {
  const int ebase = blockIdx.x * 256;
  const int dc = blockIdx.y;
  const int dbase = dc * 64;
  const int t = threadIdx.x;
  __shared__ float ql[8][64];
  const float invZ = 1.f / Z[(dc >> 1) * L + (L - 1)];   // h = dbase>>7 = dc>>1
#pragma unroll
  for (int k = 0; k < 2; ++k) {
    const int o = t + k * 256;          // [0,512): b = o>>6, dl = o&63
    const int bb = o >> 6, dl = o & 63;
    const float* __restrict__ pq = partial_q + ((size_t)bb * 32) * HS + dbase + dl;
    float a0 = 0.f, a1 = 0.f, a2 = 0.f, a3 = 0.f;
#pragma unroll 2
    for (int j4 = 0; j4 < 32; j4 += 4) {
      a0 += pq[(size_t)(j4 + 0) * HS];
      a1 += pq[(size_t)(j4 + 1) * HS];
      a2 += pq[(size_t)(j4 + 2) * HS];
      a3 += pq[(size_t)(j4 + 3) * HS];
    }
    ql[bb][dl] = ((a0 + a1) + (a2 + a3)) * invZ;
  }
  __syncthreads();
  const int e = ebase + t;
  const float* __restrict__ Ab = A + (size_t)dbase * HS + e;
  float acc[8] = {0.f, 0.f, 0.f, 0.f, 0.f, 0.f, 0.f, 0.f};
  for (int d4 = 0; d4 < 16; ++d4) {
    float4 qv[8];
#pragma unroll
    for (int bb = 0; bb < 8; ++bb) qv[bb] = *(const float4*)&ql[bb][d4 * 4];
#pragma unroll
    for (int dd = 0; dd < 4; ++dd) {
      const float a = Ab[(size_t)(d4 * 4 + dd) * HS];
      acc[0] += ((const float*)&qv[0])[dd] * a;
      acc[1] += ((const float*)&qv[1])[dd] * a;
      acc[2] += ((const float*)&qv[2])[dd] * a;
      acc[3] += ((const float*)&qv[3])[dd] * a;
      acc[4] += ((const float*)&qv[4])[dd] * a;
      acc[5] += ((const float*)&qv[5])[dd] * a;
      acc[6] += ((const float*)&qv[6])[dd] * a;
      acc[7] += ((const float*)&qv[7])[dd] * a;
    }
  }
#pragma unroll
  for (int bb = 0; bb < 8; ++bb)
    partial_v[((size_t)bb * 16 + dc) * HS + e] = acc[bb];
}

// ============ KC: fused v-reduce + u ============
__global__ __launch_bounds__(256) void kC_u(const float* __restrict__ x,
                                            const float* __restrict__ partial_v,
                                            float* __restrict__ u_pad) {
  const int b = blockIdx.x, jc = blockIdx.y;
  const int t = threadIdx.x;
  __shared__ float vs[HS];
  __shared__ float up[4][H][64];
#pragma unroll
  for (int k = 0; k < 4; ++k) {
    const int i = t + k * 256;
    float a = 0.f;
#pragma unroll
    for (int dcc = 0; dcc < 16; ++dcc) a += partial_v[((size_t)b * 16 + dcc) * HS + i];
    vs[i] = a;
  }
  __syncthreads();
  const int jl = t & 63, sq = t >> 6;
  const int j = jc * 64 + jl;
  const float4* __restrict__ xr = (const float4*)(x + ((size_t)b * L + j) * S) + sq * 8;
  float4 xv[8];
#pragma unroll
  for (int i = 0; i < 8; ++i) xv[i] = xr[i];
  float acc[H];
#pragma unroll
  for (int h = 0; h < H; ++h) {
    const float4* __restrict__ vv = (const float4*)(vs + h * S + sq * 32);
    float a = 0.f;
#pragma unroll
    for (int i = 0; i < 8; ++i) {
      const float4 w = vv[i];   // same addr across wave -> LDS broadcast
      a += xv[i].x * w.x + xv[i].y * w.y + xv[i].z * w.z + xv[i].w * w.w;
    }
    acc[h] = a;
  }
#pragma unroll
  for (int h = 0; h < H; ++h) up[sq][h][jl] = acc[h];
  __syncthreads();
#pragma unroll
  for (int k = 0; k < 2; ++k) {
    const int idx = t + k * 256;       // [0,512): h = idx>>6, j2 = idx&63
    const int h = idx >> 6, j2 = idx & 63;
    const float s = up[0][h][j2] + up[1][h][j2] + up[2][h][j2] + up[3][h][j2];
    const size_t rowbase = (size_t)(b * H + h) * (2 * L);
    u_pad[rowbase + jc * 64 + j2] = 0.f;        // zero pad (front half)
    u_pad[rowbase + L + jc * 64 + j2] = s;
  }
}

// ============ KD: conv tiles + per-(b,lt)-group gate doing score-reduce + chunk softmax stats ===
// grid B*136 triangular jobs. Gate: last block of group (b,lt) sums the lt+1 dt-slices,
// writes raw scores + chunk max (mxc) + chunk expsum (smc). Fixed-order -> deterministic.
__global__ __launch_bounds__(256) void kD_conv(const float* __restrict__ u_pad,
                                               const float* __restrict__ E,
                                               const float* __restrict__ Z,
                                               float* __restrict__ partial_s,
                                               float* __restrict__ scores,
                                               float* __restrict__ mxc,
                                               float* __restrict__ smc,
                                               unsigned* __restrict__ counters) {
  const int job = blockIdx.x;
  const int b = job / 136;
  const int rr = job - b * 136;
  int lt = 0;
  while ((lt + 1) * (lt + 2) / 2 <= rr) ++lt;
  const int dt = rr - lt * (lt + 1) / 2;
  const int l0 = lt * 128;
  const int dbase = dt * 128;
  const int t = threadIdx.x;
  const int tsub = t & 31;
  const int h = t >> 5;

  __shared__ float ech[H][128];
  __shared__ float sred[H][128];
  __shared__ float red[256];

  // stage E chunk: one float4 per thread
  {
    const int i4 = tsub * 4;
    *(float4*)&ech[h][i4] = *(const float4*)&E[h * L + dbase + i4];
  }
  __syncthreads();

  const int Lb = l0 + tsub * 4;
  const float* __restrict__ ur = u_pad + (size_t)(b * H + h) * (2 * L) + L;
  float acc0 = 0.f, acc1 = 0.f, acc2 = 0.f, acc3 = 0.f;
  float4 lo = *(const float4*)(ur + Lb - dbase - 4);
  float4 hi = *(const float4*)(ur + Lb - dbase);
#pragma unroll 4
  for (int dd = 0; dd < 128; dd += 4) {
    const float4 ev = *(const float4*)&ech[h][dd];            // LDS broadcast
    const float4 nlo = *(const float4*)(ur + Lb - (dbase + dd) - 8);
    acc0 += ev.x * hi.x; acc1 += ev.x * hi.y; acc2 += ev.x * hi.z; acc3 += ev.x * hi.w;
    acc0 += ev.y * lo.w; acc1 += ev.y * hi.x; acc2 += ev.y * hi.y; acc3 += ev.y * hi.z;
    acc0 += ev.z * lo.z; acc1 += ev.z * lo.w; acc2 += ev.z * hi.x; acc3 += ev.z * hi.y;
    acc0 += ev.w * lo.y; acc1 += ev.w * lo.z; acc2 += ev.w * lo.w; acc3 += ev.w * hi.x;
    hi = lo; lo = nlo;
  }
  const float4 zv = *(const float4*)&Z[h * L + Lb];
  sred[h][tsub * 4 + 0] = acc0 / zv.x;
  sred[h][tsub * 4 + 1] = acc1 / zv.y;
  sred[h][tsub * 4 + 2] = acc2 / zv.z;
  sred[h][tsub * 4 + 3] = acc3 / zv.w;
  __syncthreads();
  if (t < 128) {
    float sc = 0.f;
#pragma unroll
    for (int hh = 0; hh < H; ++hh) sc += sred[hh][t];
    partial_s[((size_t)b * 16 + dt) * L + l0 + t] = sc;
  }

  // --- one-shot gate: last block of group (b,lt) finalizes this l-chunk ---
  __threadfence();
  __syncthreads();
  __shared__ unsigned lastFlag;
  if (t == 0)
    lastFlag = (atomicAdd(&counters[b * 16 + lt], 1u) == (unsigned)lt) ? 1u : 0u;
  __syncthreads();
  if (lastFlag) {
    float scraw = -3.4e38f;
    if (t < 128) {
      const int l = l0 + t;
      float s = 0.f;
      for (int d2 = 0; d2 <= lt; ++d2)
        s += partial_s[((size_t)b * 16 + d2) * L + l];
      if (l != L - 1) scraw = s;
      scores[(size_t)b * L + l] = scraw;   // raw; l=L-1 stored as -3.4e38
    }
    red[t] = scraw;
    __syncthreads();
    for (int off = 128; off > 0; off >>= 1) {
      if (t < off) red[t] = fmaxf(red[t], red[t + off]);
      __syncthreads();
    }
    const float mxv = red[0];
    __syncthreads();
    red[t] = (t < 128) ? expf(scraw - mxv) : 0.f;   // -3.4e38 -> exp -> 0
    __syncthreads();
    for (int off = 128; off > 0; off >>= 1) {
      if (t < off) red[t] += red[t + off];
      __syncthreads();
    }
    if (t == 0) { mxc[b * 16 + lt] = mxv; smc[b * 16 + lt] = red[0]; }
  }
}

// ============ KF: per-block global softmax stats + weighted sums + last-block final reduce =====
__global__ __launch_bounds__(256) void kF_out(const float* __restrict__ x,
                                              const float* __restrict__ scores,
                                              const float* __restrict__ mxc,
                                              const float* __restrict__ smc,
                                              float* __restrict__ partial,
                                              unsigned* __restrict__ counters,
                                              float* __restrict__ out) {
  const int b = blockIdx.x, c = blockIdx.y;
  const int t = threadIdx.x;
  // global stats from the 16 chunk stats (uniform loads, all threads)
  float mx = -3.4e38f;
#pragma unroll
  for (int i = 0; i < 16; ++i) mx = fmaxf(mx, mxc[b * 16 + i]);
  float den = 0.f;
#pragma unroll
  for (int i = 0; i < 16; ++i) den += smc[b * 16 + i] * expf(mxc[b * 16 + i] - mx);
  const float inv = 1.f / den;

  const int s4 = t & 31;
  const int r = t >> 5;
  const int base = c * 64;
  const float4* __restrict__ x4 = (const float4*)(x + (size_t)b * L * S);
  const float* __restrict__ sb = scores + (size_t)b * L;
  float4 acc = make_float4(0.f, 0.f, 0.f, 0.f);
#pragma unroll
  for (int k = 0; k < 8; ++k) {
    const int l = base + r + k * 8;
    const float w = expf(sb[l] - mx) * inv;     // l=L-1: exp(-3.4e38-mx)=0
    const float4 xv = x4[(size_t)l * 32 + s4];
    acc.x += w * xv.x; acc.y += w * xv.y; acc.z += w * xv.z; acc.w += w * xv.w;
  }
  __shared__ float part[8][S];
  part[r][s4 * 4 + 0] = acc.x;
  part[r][s4 * 4 + 1] = acc.y;
  part[r][s4 * 4 + 2] = acc.z;
  part[r][s4 * 4 + 3] = acc.w;
  __syncthreads();
  if (t < S) {
    float sm = 0.f;
#pragma unroll
    for (int rr = 0; rr < 8; ++rr) sm += part[rr][t];
    partial[((size_t)b * 32 + c) * S + t] = sm;
  }
  // --- last-block gate (one-shot, no spinning) ---
  __threadfence();
  __syncthreads();
  __shared__ unsigned lastFlag;
  if (t == 0)
    lastFlag = (atomicAdd(&counters[128], 1u) == (unsigned)(B * 32 - 1)) ? 1u : 0u;
  __syncthreads();
  if (lastFlag) {
#pragma unroll
    for (int k = 0; k < 4; ++k) {
      const int idx = t + k * 256;   // b2 = idx>>7, s = idx&127
      const int b2 = idx >> 7, s = idx & 127;
      float a = 0.f;
      for (int cc = 0; cc < 32; ++cc) a += partial[((size_t)b2 * 32 + cc) * S + s];
      out[b2 * S + s] = a;
    }
  }
}

extern "C" void kernel_launch(void* const* d_in, const int* in_sizes, int n_in,
                              void* d_out, int out_size, void* d_ws, size_t ws_size,
                              hipStream_t stream) {
  const float* x = (const float*)d_in[0];   // (B, L, S) f32
  const float* W = (const float*)d_in[1];   // (L, H)   f32
  const float* A = (const float*)d_in[2];   // (HS, HS) f32
  float* out = (float*)d_out;               // (B, S)   f32

  float* ws        = (float*)d_ws;
  float* E         = ws;                               // H*L     = 16384
  float* Z         = E + H * L;                        // 16384
  float* partial_q = Z + H * L;                        // B*32*HS = 262144
  float* partial_v = partial_q + (size_t)B * 32 * HS;  // B*16*HS = 131072
  float* u_pad     = partial_v + (size_t)B * 16 * HS;  // B*H*2L  = 262144
  float* partial_s = u_pad + (size_t)B * H * 2 * L;    // B*16*L  = 262144
  float* scores    = partial_s + (size_t)B * 16 * L;   // B*L     = 16384
  float* mxc       = scores + (size_t)B * L;           // 128
  float* smc       = mxc + 128;                        // 128
  float* partial   = smc + 128;                        // B*32*S  = 32768
  unsigned* counters = (unsigned*)(partial + (size_t)B * 32 * S);  // 144
  // total ≈ 4 MB of d_ws

  kA_prep_qpart<<<dim3(B, 32), 256, 0, stream>>>(W, x, E, Z, partial_q, counters);
  kB_v         <<<dim3(4, 16), 256, 0, stream>>>(partial_q, Z, A, partial_v);
  kC_u         <<<dim3(B, 32), 256, 0, stream>>>(x, partial_v, u_pad);
  kD_conv      <<<B * 136,     256, 0, stream>>>(u_pad, E, Z, partial_s,
                                                 scores, mxc, smc, counters);
  kF_out       <<<dim3(B, 32), 256, 0, stream>>>(x, scores, mxc, smc,
                                                 partial, counters, out);
}

// Round 9
// 66.093 us; speedup vs baseline: 1.9961x; 1.9961x over previous
//
#include <hip/hip_runtime.h>

#define L 2048
#define H 8
#define S 128
#define B 8
#define HS 1024

// ============ KA: fused {E,Z prefix-scan} + partial_q ============
// grid (B, 32). Every block recomputes its own 64x8 exp(W) slice in LDS.
// Blocks (b==0, jc<8) additionally do the full prefix scan for h=jc -> E,Z.
__global__ __launch_bounds__(256) void kA_prep_qpart(const float* __restrict__ W,
                                                     const float* __restrict__ x,
                                                     float* __restrict__ E,
                                                     float* __restrict__ Z,
                                                     float* __restrict__ partial_q,
                                                     unsigned* __restrict__ counters) {
  const int b = blockIdx.x, jc = blockIdx.y;
  const int t = threadIdx.x;
  if (b == 0 && jc == 0 && t == 0) counters[0] = 0u;   // kF last-block gate

  __shared__ float ew[64][H];       // ew[i][h] = E[h, L-1-(base+i)]
  __shared__ float part[8][H][S];   // [r][h][s]
  __shared__ float tot[256];        // scan scratch

  const int base = jc * 64;
  const int dhi = L - 1 - base;
#pragma unroll
  for (int k = 0; k < 2; ++k) {
    const int idx = t + k * 256;    // [0,512): i = idx>>3, h = idx&7
    const int i = idx >> 3, h = idx & 7;
    ew[i][h] = expf(W[(size_t)(dhi - i) * H + h]);
  }

  // --- full prefix scan for one h (8 blocks only) ---
  if (b == 0 && jc < H) {
    const int h = jc;
    const int d0 = t * 8;
    float e[8];
    float run = 0.f;
#pragma unroll
    for (int k = 0; k < 8; ++k) {
      float v = expf(W[(size_t)(d0 + k) * H + h]);
      e[k] = v; run += v;
    }
    tot[t] = run;
    __syncthreads();
    for (int off = 1; off < 256; off <<= 1) {
      float v = (t >= off) ? tot[t - off] : 0.f;
      __syncthreads();
      tot[t] += v;
      __syncthreads();
    }
    float c = (t == 0) ? 0.f : tot[t - 1];
#pragma unroll
    for (int k = 0; k < 8; ++k) {
      c += e[k];
      E[h * L + d0 + k] = e[k];
      Z[h * L + d0 + k] = c;
    }
  }
  __syncthreads();   // ew ready (and scan done)

  // --- partial_q main loop ---
  const int s4 = t & 31;
  const int r = t >> 5;
  const float4* __restrict__ x4 = (const float4*)(x + (size_t)b * L * S);
  float4 acc[H];
#pragma unroll
  for (int h = 0; h < H; ++h) acc[h] = make_float4(0.f, 0.f, 0.f, 0.f);
#pragma unroll
  for (int k = 0; k < 8; ++k) {
    const int ll = k * 8 + r;
    const int l = base + ll;
    const float4 xv = x4[(size_t)l * 32 + s4];
#pragma unroll
    for (int h = 0; h < H; ++h) {
      const float w = ew[ll][h];
      acc[h].x += w * xv.x; acc[h].y += w * xv.y;
      acc[h].z += w * xv.z; acc[h].w += w * xv.w;
    }
  }
#pragma unroll
  for (int h = 0; h < H; ++h) {
    part[r][h][s4 * 4 + 0] = acc[h].x;
    part[r][h][s4 * 4 + 1] = acc[h].y;
    part[r][h][s4 * 4 + 2] = acc[h].z;
    part[r][h][s4 * 4 + 3] = acc[h].w;
  }
  __syncthreads();
#pragma unroll
  for (int k = 0; k < 4; ++k) {
    const int idx = t + k * 256;           // h*S + s
    const int h = idx >> 7, s = idx & 127;
    float sm = 0.f;
#pragma unroll
    for (int rr = 0; rr < 8; ++rr) sm += part[rr][h][s];
    partial_q[((size_t)b * 32 + jc) * HS + idx] = sm;
  }
}

// ============ KB: all-batch GEMV over one A-chunk ============
// grid (4 ec, 16 dc). Phase 1: ql[b][dl] from partial_q (invZ folded, h uniform/block).
// Phase 2: partial_v[b,dc,e] = sum_d ql[b][d] * A[dbase+d, e]. A traffic = 4 MB total.
__global__ __launch_bounds__(256) void kB_v(const float* __restrict__ partial_q,
                                            const float* __restrict__ Z,
                                            const float* __restrict__ A,
                                            float* __restrict__ partial_v) {
  const int ebase = blockIdx.x * 256;
  const int dc = blockIdx.y;
  const int dbase = dc * 64;
  const int t = threadIdx.x;
  __shared__ float ql[8][64];
  const float invZ = 1.f / Z[(dc >> 1) * L + (L - 1)];   // h = dbase>>7 = dc>>1
#pragma unroll
  for (int k = 0; k < 2; ++k) {
    const int o = t + k * 256;          // [0,512): b = o>>6, dl = o&63
    const int bb = o >> 6, dl = o & 63;
    const float* __restrict__ pq = partial_q + ((size_t)bb * 32) * HS + dbase + dl;
    float a0 = 0.f, a1 = 0.f, a2 = 0.f, a3 = 0.f;
#pragma unroll 2
    for (int j4 = 0; j4 < 32; j4 += 4) {
      a0 += pq[(size_t)(j4 + 0) * HS];
      a1 += pq[(size_t)(j4 + 1) * HS];
      a2 += pq[(size_t)(j4 + 2) * HS];
      a3 += pq[(size_t)(j4 + 3) * HS];
    }
    ql[bb][dl] = ((a0 + a1) + (a2 + a3)) * invZ;
  }
  __syncthreads();
  const int e = ebase + t;
  const float* __restrict__ Ab = A + (size_t)dbase * HS + e;
  float acc[8] = {0.f, 0.f, 0.f, 0.f, 0.f, 0.f, 0.f, 0.f};
  for (int d4 = 0; d4 < 16; ++d4) {
    float4 qv[8];
#pragma unroll
    for (int bb = 0; bb < 8; ++bb) qv[bb] = *(const float4*)&ql[bb][d4 * 4];
#pragma unroll
    for (int dd = 0; dd < 4; ++dd) {
      const float a = Ab[(size_t)(d4 * 4 + dd) * HS];
      acc[0] += ((const float*)&qv[0])[dd] * a;
      acc[1] += ((const float*)&qv[1])[dd] * a;
      acc[2] += ((const float*)&qv[2])[dd] * a;
      acc[3] += ((const float*)&qv[3])[dd] * a;
      acc[4] += ((const float*)&qv[4])[dd] * a;
      acc[5] += ((const float*)&qv[5])[dd] * a;
      acc[6] += ((const float*)&qv[6])[dd] * a;
      acc[7] += ((const float*)&qv[7])[dd] * a;
    }
  }
#pragma unroll
  for (int bb = 0; bb < 8; ++bb)
    partial_v[((size_t)bb * 16 + dc) * HS + e] = acc[bb];
}

// ============ KC: fused v-reduce + u ============
__global__ __launch_bounds__(256) void kC_u(const float* __restrict__ x,
                                            const float* __restrict__ partial_v,
                                            float* __restrict__ u_pad) {
  const int b = blockIdx.x, jc = blockIdx.y;
  const int t = threadIdx.x;
  __shared__ float vs[HS];
  __shared__ float up[4][H][64];
#pragma unroll
  for (int k = 0; k < 4; ++k) {
    const int i = t + k * 256;
    float a = 0.f;
#pragma unroll
    for (int dcc = 0; dcc < 16; ++dcc) a += partial_v[((size_t)b * 16 + dcc) * HS + i];
    vs[i] = a;
  }
  __syncthreads();
  const int jl = t & 63, sq = t >> 6;
  const int j = jc * 64 + jl;
  const float4* __restrict__ xr = (const float4*)(x + ((size_t)b * L + j) * S) + sq * 8;
  float4 xv[8];
#pragma unroll
  for (int i = 0; i < 8; ++i) xv[i] = xr[i];
  float acc[H];
#pragma unroll
  for (int h = 0; h < H; ++h) {
    const float4* __restrict__ vv = (const float4*)(vs + h * S + sq * 32);
    float a = 0.f;
#pragma unroll
    for (int i = 0; i < 8; ++i) {
      const float4 w = vv[i];   // same addr across wave -> LDS broadcast
      a += xv[i].x * w.x + xv[i].y * w.y + xv[i].z * w.z + xv[i].w * w.w;
    }
    acc[h] = a;
  }
#pragma unroll
  for (int h = 0; h < H; ++h) up[sq][h][jl] = acc[h];
  __syncthreads();
#pragma unroll
  for (int k = 0; k < 2; ++k) {
    const int idx = t + k * 256;       // [0,512): h = idx>>6, j2 = idx&63
    const int h = idx >> 6, j2 = idx & 63;
    const float s = up[0][h][j2] + up[1][h][j2] + up[2][h][j2] + up[3][h][j2];
    const size_t rowbase = (size_t)(b * H + h) * (2 * L);
    u_pad[rowbase + jc * 64 + j2] = 0.f;        // zero pad (front half)
    u_pad[rowbase + L + jc * 64 + j2] = s;
  }
}

// ============ KD: conv partials, flat triangular grid of B*136 blocks (NO gate/fence) ==========
__global__ __launch_bounds__(256) void kD_conv(const float* __restrict__ u_pad,
                                               const float* __restrict__ E,
                                               const float* __restrict__ Z,
                                               float* __restrict__ partial_s) {
  const int job = blockIdx.x;
  const int b = job / 136;
  const int rr = job - b * 136;
  int lt = 0;
  while ((lt + 1) * (lt + 2) / 2 <= rr) ++lt;
  const int dt = rr - lt * (lt + 1) / 2;
  const int l0 = lt * 128;
  const int dbase = dt * 128;
  const int t = threadIdx.x;
  const int tsub = t & 31;
  const int h = t >> 5;
  const int Lb = l0 + tsub * 4;
  const float* __restrict__ ur = u_pad + (size_t)(b * H + h) * (2 * L) + L;
  const float4* __restrict__ Eh4 = (const float4*)(E + h * L);
  float acc0 = 0.f, acc1 = 0.f, acc2 = 0.f, acc3 = 0.f;
  float4 lo = *(const float4*)(ur + Lb - dbase - 4);
  float4 hi = *(const float4*)(ur + Lb - dbase);
#pragma unroll 4
  for (int dd = 0; dd < 128; dd += 4) {
    const int d0 = dbase + dd;
    float4 ev  = Eh4[d0 >> 2];                        // wave-uniform -> scalar load
    float4 nlo = *(const float4*)(ur + Lb - d0 - 8);
    acc0 += ev.x * hi.x; acc1 += ev.x * hi.y; acc2 += ev.x * hi.z; acc3 += ev.x * hi.w;
    acc0 += ev.y * lo.w; acc1 += ev.y * hi.x; acc2 += ev.y * hi.y; acc3 += ev.y * hi.z;
    acc0 += ev.z * lo.z; acc1 += ev.z * lo.w; acc2 += ev.z * hi.x; acc3 += ev.z * hi.y;
    acc0 += ev.w * lo.y; acc1 += ev.w * lo.z; acc2 += ev.w * lo.w; acc3 += ev.w * hi.x;
    hi = lo; lo = nlo;
  }
  __shared__ float sred[H][128];
  const float4 zv = *(const float4*)&Z[h * L + Lb];
  sred[h][tsub * 4 + 0] = acc0 / zv.x;
  sred[h][tsub * 4 + 1] = acc1 / zv.y;
  sred[h][tsub * 4 + 2] = acc2 / zv.z;
  sred[h][tsub * 4 + 3] = acc3 / zv.w;
  __syncthreads();
  if (t < 128) {
    float sc = 0.f;
#pragma unroll
    for (int hh = 0; hh < H; ++hh) sc += sred[hh][t];
    partial_s[((size_t)b * 16 + dt) * L + l0 + t] = sc;
  }
}

// ============ KF: redundant per-block softmax (from partial_s) + weighted sum + final reduce ===
// grid (B, 32). Phase A: every block computes its batch's full softmax weights into LDS
// (redundant across the 32 blocks of a batch — parallel, no sync). Phase B: weighted x sum.
__global__ __launch_bounds__(256) void kF_out(const float* __restrict__ x,
                                              const float* __restrict__ partial_s,
                                              float* __restrict__ partial,
                                              unsigned* __restrict__ counters,
                                              float* __restrict__ out) {
  const int b = blockIdx.x, c = blockIdx.y;
  const int t = threadIdx.x;
  __shared__ float ep[L];          // normalized weights
  __shared__ float red[256];
  __shared__ float part[8][S];

  // --- Phase A: scores -> softmax weights (thread t owns l in [8t, 8t+8)) ---
  const int l0 = t * 8;
  const int lt = t >> 4;                 // (8t)>>7
  float sc[8];
#pragma unroll
  for (int k = 0; k < 8; ++k) sc[k] = 0.f;
  for (int dt = 0; dt <= lt; ++dt) {
    const float4* __restrict__ ps = (const float4*)(partial_s + ((size_t)b * 16 + dt) * L + l0);
    const float4 a = ps[0], c4 = ps[1];
    sc[0] += a.x;  sc[1] += a.y;  sc[2] += a.z;  sc[3] += a.w;
    sc[4] += c4.x; sc[5] += c4.y; sc[6] += c4.z; sc[7] += c4.w;
  }
  if (t == 255) sc[7] = -3.4e38f;        // l = 2047 excluded
  float mx = sc[0];
#pragma unroll
  for (int k = 1; k < 8; ++k) mx = fmaxf(mx, sc[k]);
  red[t] = mx;
  __syncthreads();
  for (int off = 128; off > 0; off >>= 1) {
    if (t < off) red[t] = fmaxf(red[t], red[t + off]);
    __syncthreads();
  }
  mx = red[0];
  __syncthreads();
  float e[8];
  float sm = 0.f;
#pragma unroll
  for (int k = 0; k < 8; ++k) {
    e[k] = (l0 + k < L - 1) ? expf(sc[k] - mx) : 0.f;
    sm += e[k];
  }
  red[t] = sm;
  __syncthreads();
  for (int off = 128; off > 0; off >>= 1) {
    if (t < off) red[t] += red[t + off];
    __syncthreads();
  }
  const float inv = 1.f / red[0];
#pragma unroll
  for (int k = 0; k < 8; ++k) ep[l0 + k] = e[k] * inv;
  __syncthreads();

  // --- Phase B: partial[b,c,s] = sum_{l in chunk c} ep[l] * x[b,l,s] ---
  const int s4 = t & 31;
  const int r = t >> 5;
  const int base = c * 64;
  const float4* __restrict__ x4 = (const float4*)(x + (size_t)b * L * S);
  float4 acc = make_float4(0.f, 0.f, 0.f, 0.f);
#pragma unroll
  for (int k = 0; k < 8; ++k) {
    const int l = base + r + k * 8;
    const float w = ep[l];
    const float4 xv = x4[(size_t)l * 32 + s4];
    acc.x += w * xv.x; acc.y += w * xv.y; acc.z += w * xv.z; acc.w += w * xv.w;
  }
  part[r][s4 * 4 + 0] = acc.x;
  part[r][s4 * 4 + 1] = acc.y;
  part[r][s4 * 4 + 2] = acc.z;
  part[r][s4 * 4 + 3] = acc.w;
  __syncthreads();
  if (t < S) {
    float smv = 0.f;
#pragma unroll
    for (int rr = 0; rr < 8; ++rr) smv += part[rr][t];
    partial[((size_t)b * 32 + c) * S + t] = smv;
  }
  // --- last-block gate (one-shot, 256 blocks — proven cheap) ---
  __threadfence();
  __syncthreads();
  __shared__ unsigned lastFlag;
  if (t == 0)
    lastFlag = (atomicAdd(&counters[0], 1u) == (unsigned)(B * 32 - 1)) ? 1u : 0u;
  __syncthreads();
  if (lastFlag) {
#pragma unroll
    for (int k = 0; k < 4; ++k) {
      const int idx = t + k * 256;   // b2 = idx>>7, s = idx&127
      const int b2 = idx >> 7, s = idx & 127;
      float a = 0.f;
      for (int cc = 0; cc < 32; ++cc) a += partial[((size_t)b2 * 32 + cc) * S + s];
      out[b2 * S + s] = a;
    }
  }
}

extern "C" void kernel_launch(void* const* d_in, const int* in_sizes, int n_in,
                              void* d_out, int out_size, void* d_ws, size_t ws_size,
                              hipStream_t stream) {
  const float* x = (const float*)d_in[0];   // (B, L, S) f32
  const float* W = (const float*)d_in[1];   // (L, H)   f32
  const float* A = (const float*)d_in[2];   // (HS, HS) f32
  float* out = (float*)d_out;               // (B, S)   f32

  float* ws        = (float*)d_ws;
  float* E         = ws;                               // H*L     = 16384
  float* Z         = E + H * L;                        // 16384
  float* partial_q = Z + H * L;                        // B*32*HS = 262144
  float* partial_v = partial_q + (size_t)B * 32 * HS;  // B*16*HS = 131072
  float* u_pad     = partial_v + (size_t)B * 16 * HS;  // B*H*2L  = 262144
  float* partial_s = u_pad + (size_t)B * H * 2 * L;    // B*16*L  = 262144
  float* partial   = partial_s + (size_t)B * 16 * L;   // B*32*S  = 32768
  unsigned* counters = (unsigned*)(partial + (size_t)B * 32 * S);
  // total ≈ 3.9 MB of d_ws

  kA_prep_qpart<<<dim3(B, 32), 256, 0, stream>>>(W, x, E, Z, partial_q, counters);
  kB_v         <<<dim3(4, 16), 256, 0, stream>>>(partial_q, Z, A, partial_v);
  kC_u         <<<dim3(B, 32), 256, 0, stream>>>(x, partial_v, u_pad);
  kD_conv      <<<B * 136,     256, 0, stream>>>(u_pad, E, Z, partial_s);
  kF_out       <<<dim3(B, 32), 256, 0, stream>>>(x, partial_s, partial, counters, out);
}